// Round 7
// baseline (208.766 us; speedup 1.0000x reference)
//
#include <hip/hip_runtime.h>
#include <hip/hip_bf16.h>
#include <math.h>

#define TB 2048   // sequence length
#define NB 4      // batch
#define NH 8      // heads
#define HD 96     // head dim
#define KD 768    // model dim

typedef unsigned short u16;
typedef __attribute__((ext_vector_type(4))) u16 u16x4;
typedef __attribute__((ext_vector_type(8))) u16 u16x8;
typedef __attribute__((ext_vector_type(4))) float f32x4;
typedef __attribute__((ext_vector_type(16))) float f32x16;
typedef __attribute__((ext_vector_type(4))) unsigned u32x4;
typedef __attribute__((ext_vector_type(8))) __bf16 bf16x8;

__device__ __forceinline__ u16 f2bf(float f) {
    unsigned u = __builtin_bit_cast(unsigned, f);
    u += 0x7FFFu + ((u >> 16) & 1u);   // RNE
    return (u16)(u >> 16);
}
__device__ __forceinline__ bf16x8 cast8(u16x8 u) { return __builtin_bit_cast(bf16x8, u); }
__device__ __forceinline__ unsigned pkbf(float a, float b) {
    unsigned w;
    asm("v_cvt_pk_bf16_f32 %0, %1, %2" : "=v"(w) : "v"(a), "v"(b));
    return w;
}

// ---------------------------------------------------------------------------
// Kernel A: QKV projection.  Block = one (b,h,t-chunk of 64).
//   Q,K -> [bh][t][96]   (D = x*W^T, rows = t)
//   V   -> [bh][96][t]   (transposed: D = W*x^T via swapped MFMA args)
// inv4 baked into Wq,Wk.  grid = (32 t-chunks, 32 bh), 256 thr.
// ---------------------------------------------------------------------------
__global__ __launch_bounds__(256) void qkv_proj(
    const float* __restrict__ x, const float* __restrict__ Wq,
    const float* __restrict__ Wk, const float* __restrict__ Wv,
    u16* __restrict__ Q, u16* __restrict__ Kout, u16* __restrict__ VT, float inv4)
{
    __shared__ __align__(16) u16 Wl[3][96][104];
    const int tid = threadIdx.x;
    for (int idx = tid; idx < 3 * 9216; idx += 256) {
        int m = idx / 9216, rem = idx % 9216;
        const float* Wsrc = (m == 0) ? Wq : (m == 1) ? Wk : Wv;
        float scale = (m < 2) ? inv4 : 1.0f;
        int r = rem / 96, c = rem % 96;
        Wl[m][r][c] = f2bf(Wsrc[rem] * scale);
    }
    __syncthreads();

    const int w = tid >> 6, l = tid & 63;
    const int lc = l & 15, lk = l >> 4;
    const int bh = blockIdx.y, b = bh >> 3, h = bh & 7;
    const int t0 = blockIdx.x * 64 + w * 16;

    bf16x8 afrag[3];
    {
        const float* xp = x + ((long)((b * TB + t0 + lc) * NH + h)) * HD + 8 * lk;
#pragma unroll
        for (int c = 0; c < 3; ++c) {
            f32x4 f0 = *(const f32x4*)(xp + c * 32);
            f32x4 f1 = *(const f32x4*)(xp + c * 32 + 4);
            u16x8 u;
#pragma unroll
            for (int j = 0; j < 4; ++j) { u[j] = f2bf(f0[j]); u[4 + j] = f2bf(f1[j]); }
            afrag[c] = cast8(u);
        }
    }

    const f32x4 Z4 = {0.f, 0.f, 0.f, 0.f};
    u16* outs[2] = {Q, Kout};
#pragma unroll
    for (int m = 0; m < 2; ++m) {
        f32x4 acc[6];
#pragma unroll
        for (int nt = 0; nt < 6; ++nt) acc[nt] = Z4;
#pragma unroll
        for (int c = 0; c < 3; ++c) {
#pragma unroll
            for (int nt = 0; nt < 6; ++nt) {
                u16x8 bw = *(const u16x8*)&Wl[m][nt * 16 + lc][c * 32 + 8 * lk];
                acc[nt] = __builtin_amdgcn_mfma_f32_16x16x32_bf16(afrag[c], cast8(bw), acc[nt], 0, 0, 0);
            }
        }
#pragma unroll
        for (int reg = 0; reg < 4; ++reg) {
            int t = t0 + lk * 4 + reg;
            u16* op = outs[m] + ((long)bh * TB + t) * HD;
#pragma unroll
            for (int nt = 0; nt < 6; ++nt)
                op[nt * 16 + lc] = f2bf(acc[nt][reg]);
        }
    }
    {   // V transposed
        f32x4 acc[6];
#pragma unroll
        for (int nt = 0; nt < 6; ++nt) acc[nt] = Z4;
#pragma unroll
        for (int c = 0; c < 3; ++c) {
#pragma unroll
            for (int nt = 0; nt < 6; ++nt) {
                u16x8 aw = *(const u16x8*)&Wl[2][nt * 16 + lc][c * 32 + 8 * lk];
                acc[nt] = __builtin_amdgcn_mfma_f32_16x16x32_bf16(cast8(aw), afrag[c], acc[nt], 0, 0, 0);
            }
        }
#pragma unroll
        for (int nt = 0; nt < 6; ++nt)
#pragma unroll
            for (int reg = 0; reg < 4; ++reg) {
                int o = nt * 16 + lk * 4 + reg;
                VT[((long)bh * HD + o) * TB + t0 + lc] = f2bf(acc[nt][reg]);
            }
    }
}

// ---------------------------------------------------------------------------
// Kernel B: flash attention, 32x32 MFMA.  4-wave blocks (q-tile 128), K/V
// tile 64, double-buffered LDS with ONE barrier/step, XCD-swizzled 1D grid
// (512 blocks = 2/CU).  Swapped QK^T, in-register P rebuild, T13 defer-max.
// ---------------------------------------------------------------------------
#define KOFF 0
#define VOFF (64 * 104)
#define SLAB (64 * 104 + 96 * 72)

__global__ __launch_bounds__(256) void attn(
    const u16* __restrict__ Q, const u16* __restrict__ Kin, const u16* __restrict__ VT,
    u16* __restrict__ O)
{
    __shared__ __align__(16) u16 SM[2][SLAB];

    const int tid = threadIdx.x;
    const int w = tid >> 6, l = tid & 63;
    const int m32 = l & 31, hi = l >> 5;
    // XCD swizzle: 16 q-tiles of one bh land on one XCD (512 % 8 == 0)
    const int lid = (blockIdx.x & 7) * 64 + (blockIdx.x >> 3);
    const int qt = lid & 15, bh = lid >> 4;
    const int q0 = qt * 128 + w * 32;

    const u16* Qb = Q + (long)bh * TB * HD;
    const u16* Kb = Kin + (long)bh * TB * HD;
    const u16* Vb = VT + (long)bh * HD * TB;    // [d][t]

    // staging: 6 b128 chunks/thread (K: 768 chunks, Vt: 768)
    const u16* gbase[6]; int loff[6]; int mult[6];
#pragma unroll
    for (int ci = 0; ci < 6; ++ci) {
        int ch = tid + ci * 256;
        if (ch < 768) {
            int row = ch / 12, cc = (ch % 12) * 8;
            gbase[ci] = Kb + row * HD + cc;
            mult[ci] = HD;
            loff[ci] = KOFF + row * 104 + cc;
        } else {
            int c2 = ch - 768;
            int d = c2 >> 3, sc = (c2 & 7) * 8;
            gbase[ci] = Vb + (long)d * TB + sc;
            mult[ci] = 1;
            loff[ci] = VOFF + d * 72 + sc;
        }
    }

    // Q B-fragments: col q = q0+m32, k = kk*16 + 8*hi + j
    bf16x8 qb[6];
#pragma unroll
    for (int kk = 0; kk < 6; ++kk)
        qb[kk] = cast8(*(const u16x8*)(Qb + (long)(q0 + m32) * HD + kk * 16 + 8 * hi));

    // prologue: tile0 -> SM[0], prefetch tile1 into regs
    u16x8 r[6];
#pragma unroll
    for (int ci = 0; ci < 6; ++ci) r[ci] = *(const u16x8*)(gbase[ci]);
#pragma unroll
    for (int ci = 0; ci < 6; ++ci) *(u16x8*)(SM[0] + loff[ci]) = r[ci];
#pragma unroll
    for (int ci = 0; ci < 6; ++ci) r[ci] = *(const u16x8*)(gbase[ci] + (long)64 * mult[ci]);

    float m_st = -1e30f, l_st = 0.f;    // per-lane: q = q0 + m32
    f32x16 accO[3];                      // O^T[d-tile][q]
#pragma unroll
    for (int dt = 0; dt < 3; ++dt)
#pragma unroll
        for (int rr = 0; rr < 16; ++rr) accO[dt][rr] = 0.f;

    for (int st = 0; st < TB / 64; ++st) {
        __syncthreads();   // all waves done step st-1 (reads of parity (st+1)&1 complete)
        if (st < TB / 64 - 1) {
            u16* dst = SM[(st + 1) & 1];
#pragma unroll
            for (int ci = 0; ci < 6; ++ci) *(u16x8*)(dst + loff[ci]) = r[ci];
            int s2 = (st + 2 < TB / 64 ? st + 2 : TB / 64 - 1) * 64;
#pragma unroll
            for (int ci = 0; ci < 6; ++ci) r[ci] = *(const u16x8*)(gbase[ci] + (long)s2 * mult[ci]);
        }
        const u16* KP = SM[st & 1] + KOFF;
        const u16* VP = SM[st & 1] + VOFF;

        // S^T = K Q^T, 32x32x16: A = K rows (s), B = Q cols (q)
        f32x16 sa[2];
        __builtin_amdgcn_s_setprio(1);
#pragma unroll
        for (int st2 = 0; st2 < 2; ++st2) {
#pragma unroll
            for (int rr = 0; rr < 16; ++rr) sa[st2][rr] = 0.f;
#pragma unroll
            for (int kk = 0; kk < 6; ++kk) {
                u16x8 kf = *(const u16x8*)(KP + (st2 * 32 + m32) * 104 + kk * 16 + 8 * hi);
                sa[st2] = __builtin_amdgcn_mfma_f32_32x32x16_bf16(cast8(kf), qb[kk], sa[st2], 0, 0, 0);
            }
        }
        __builtin_amdgcn_s_setprio(0);

        // softmax: lane holds 32 s-values of q's column; other 32 at lane^32
        float tm = sa[0][0];
#pragma unroll
        for (int st2 = 0; st2 < 2; ++st2)
#pragma unroll
            for (int rr = 0; rr < 16; ++rr) tm = fmaxf(tm, sa[st2][rr]);
        tm = fmaxf(tm, __shfl_xor(tm, 32));
        if (!__all(tm - m_st <= 8.0f)) {   // T13 defer-max
            float mnew = fmaxf(m_st, tm);
            float alpha = __expf(m_st - mnew);
#pragma unroll
            for (int dt = 0; dt < 3; ++dt)
#pragma unroll
                for (int rr = 0; rr < 16; ++rr) accO[dt][rr] *= alpha;
            l_st *= alpha;
            m_st = mnew;
        }
        float sum = 0.f;
#pragma unroll
        for (int st2 = 0; st2 < 2; ++st2)
#pragma unroll
            for (int rr = 0; rr < 16; ++rr) {
                float pv = __expf(sa[st2][rr] - m_st);
                sa[st2][rr] = pv;
                sum += pv;
            }
        sum += __shfl_xor(sum, 32);
        l_st += sum;

        // P -> bf16 B-fragments in-register; PV accumulate
#pragma unroll
        for (int st2 = 0; st2 < 2; ++st2) {
            unsigned A1 = pkbf(sa[st2][0], sa[st2][1]);
            unsigned A2 = pkbf(sa[st2][2], sa[st2][3]);
            unsigned B1 = pkbf(sa[st2][4], sa[st2][5]);
            unsigned B2 = pkbf(sa[st2][6], sa[st2][7]);
            unsigned A3 = pkbf(sa[st2][8], sa[st2][9]);
            unsigned A4 = pkbf(sa[st2][10], sa[st2][11]);
            unsigned B3 = pkbf(sa[st2][12], sa[st2][13]);
            unsigned B4 = pkbf(sa[st2][14], sa[st2][15]);
            unsigned xA1 = __shfl_xor((int)A1, 32), xA2 = __shfl_xor((int)A2, 32);
            unsigned xB1 = __shfl_xor((int)B1, 32), xB2 = __shfl_xor((int)B2, 32);
            unsigned xA3 = __shfl_xor((int)A3, 32), xA4 = __shfl_xor((int)A4, 32);
            unsigned xB3 = __shfl_xor((int)B3, 32), xB4 = __shfl_xor((int)B4, 32);
            u32x4 t0 = { hi ? xB1 : A1, hi ? xB2 : A2, hi ? B1 : xA1, hi ? B2 : xA2 };
            u32x4 t1 = { hi ? xB3 : A3, hi ? xB4 : A4, hi ? B3 : xA3, hi ? B4 : xA4 };
            bf16x8 pb0 = __builtin_bit_cast(bf16x8, t0);   // k = st2*32 + 0..15
            bf16x8 pb1 = __builtin_bit_cast(bf16x8, t1);   // k = st2*32 + 16..31
            __builtin_amdgcn_s_setprio(1);
#pragma unroll
            for (int dt = 0; dt < 3; ++dt) {
                u16x8 vfa = *(const u16x8*)(VP + (dt * 32 + m32) * 72 + st2 * 32 + 8 * hi);
                accO[dt] = __builtin_amdgcn_mfma_f32_32x32x16_bf16(cast8(vfa), pb0, accO[dt], 0, 0, 0);
            }
#pragma unroll
            for (int dt = 0; dt < 3; ++dt) {
                u16x8 vfb = *(const u16x8*)(VP + (dt * 32 + m32) * 72 + st2 * 32 + 16 + 8 * hi);
                accO[dt] = __builtin_amdgcn_mfma_f32_32x32x16_bf16(cast8(vfb), pb1, accO[dt], 0, 0, 0);
            }
            __builtin_amdgcn_s_setprio(0);
        }
    }

    // epilogue: O^T[d][q] -> O[b][t=q][h*96+d], /= l_st
    const int b = bh >> 3, h = bh & 7;
    float linv = 1.0f / l_st;
    int t = q0 + m32;
    u16* op = O + ((long)(b * TB + t)) * KD + h * HD;
#pragma unroll
    for (int dt = 0; dt < 3; ++dt)
#pragma unroll
        for (int q4 = 0; q4 < 4; ++q4) {
            u16x4 v = { f2bf(accO[dt][q4 * 4 + 0] * linv), f2bf(accO[dt][q4 * 4 + 1] * linv),
                        f2bf(accO[dt][q4 * 4 + 2] * linv), f2bf(accO[dt][q4 * 4 + 3] * linv) };
            *(u16x4*)(op + dt * 32 + q4 * 8 + 4 * hi) = v;
        }
}

// ---------------------------------------------------------------------------
// Kernel C0: one-time Wu fp32 -> bf16 (into dead Q workspace region)
// ---------------------------------------------------------------------------
__global__ __launch_bounds__(256) void wu_conv(const float* __restrict__ Wu, u16* __restrict__ Wub) {
    int i = (blockIdx.x * 256 + threadIdx.x) * 4;
    f32x4 f = *(const f32x4*)(Wu + i);
    u16x4 o = { f2bf(f[0]), f2bf(f[1]), f2bf(f[2]), f2bf(f[3]) };
    *(u16x4*)(Wub + i) = o;
}

// ---------------------------------------------------------------------------
// Kernel C: out = O @ Wub^T + bu.  M=8192, N=768, K=768.  128x128 tile,
// BK=64, 32x32 MFMA, dbuf single-barrier, reg-prefetch.  4 waves (2x2),
// wave tile 64x64.  1D grid 384 = 48/XCD, nb-major swizzle.
// ---------------------------------------------------------------------------
__global__ __launch_bounds__(256) void out_gemm(
    const u16* __restrict__ O, const u16* __restrict__ Wub,
    const float* __restrict__ bu, float* __restrict__ out)
{
    __shared__ __align__(16) u16 Al[2][128][68];
    __shared__ __align__(16) u16 Bl[2][128][68];
    const int tid = threadIdx.x;
    const int w = tid >> 6, l = tid & 63;
    const int m32 = l & 31, hi = l >> 5;
    const int wr = w >> 1, wc = w & 1;
    const int lid = (blockIdx.x & 7) * 48 + (blockIdx.x >> 3);
    const int nb = lid % 6, mb = lid / 6;
    const int m0 = mb * 128, n0 = nb * 128;

    const int crow = tid >> 3, ccol = (tid & 7) * 8;   // 4 chunks: +32 rows each

    f32x16 acc[2][2];
#pragma unroll
    for (int i = 0; i < 2; ++i)
#pragma unroll
        for (int j = 0; j < 2; ++j)
#pragma unroll
            for (int rr = 0; rr < 16; ++rr) acc[i][j][rr] = 0.f;

    // prologue: k-slab 0 -> LDS[0], prefetch slab 1
    u16x8 ra[4], rb[4];
#pragma unroll
    for (int i = 0; i < 4; ++i) {
        ra[i] = *(const u16x8*)(O   + (long)(m0 + crow + i * 32) * KD + ccol);
        rb[i] = *(const u16x8*)(Wub + (long)(n0 + crow + i * 32) * KD + ccol);
    }
#pragma unroll
    for (int i = 0; i < 4; ++i) {
        *(u16x8*)&Al[0][crow + i * 32][ccol] = ra[i];
        *(u16x8*)&Bl[0][crow + i * 32][ccol] = rb[i];
    }
#pragma unroll
    for (int i = 0; i < 4; ++i) {
        ra[i] = *(const u16x8*)(O   + (long)(m0 + crow + i * 32) * KD + 64 + ccol);
        rb[i] = *(const u16x8*)(Wub + (long)(n0 + crow + i * 32) * KD + 64 + ccol);
    }

    for (int kt = 0; kt < KD / 64; ++kt) {
        __syncthreads();
        if (kt < KD / 64 - 1) {
            int p = (kt + 1) & 1;
#pragma unroll
            for (int i = 0; i < 4; ++i) {
                *(u16x8*)&Al[p][crow + i * 32][ccol] = ra[i];
                *(u16x8*)&Bl[p][crow + i * 32][ccol] = rb[i];
            }
            int cn = (kt + 2 < KD / 64 ? kt + 2 : KD / 64 - 1) * 64;
#pragma unroll
            for (int i = 0; i < 4; ++i) {
                ra[i] = *(const u16x8*)(O   + (long)(m0 + crow + i * 32) * KD + cn + ccol);
                rb[i] = *(const u16x8*)(Wub + (long)(n0 + crow + i * 32) * KD + cn + ccol);
            }
        }
        int p = kt & 1;
        __builtin_amdgcn_s_setprio(1);
#pragma unroll
        for (int k16 = 0; k16 < 4; ++k16) {
            bf16x8 afr[2], bfr[2];
#pragma unroll
            for (int rb2 = 0; rb2 < 2; ++rb2)
                afr[rb2] = cast8(*(const u16x8*)&Al[p][wr * 64 + rb2 * 32 + m32][k16 * 16 + 8 * hi]);
#pragma unroll
            for (int cb2 = 0; cb2 < 2; ++cb2)
                bfr[cb2] = cast8(*(const u16x8*)&Bl[p][wc * 64 + cb2 * 32 + m32][k16 * 16 + 8 * hi]);
#pragma unroll
            for (int rb2 = 0; rb2 < 2; ++rb2)
#pragma unroll
                for (int cb2 = 0; cb2 < 2; ++cb2)
                    acc[rb2][cb2] = __builtin_amdgcn_mfma_f32_32x32x16_bf16(afr[rb2], bfr[cb2], acc[rb2][cb2], 0, 0, 0);
        }
        __builtin_amdgcn_s_setprio(0);
    }

    const float bv0 = bu[n0 + wc * 64 + m32];
    const float bv1 = bu[n0 + wc * 64 + 32 + m32];
#pragma unroll
    for (int rb2 = 0; rb2 < 2; ++rb2)
#pragma unroll
        for (int cb2 = 0; cb2 < 2; ++cb2) {
            float bv = cb2 ? bv1 : bv0;
            int nn = n0 + wc * 64 + cb2 * 32 + m32;
#pragma unroll
            for (int reg = 0; reg < 16; ++reg) {
                int mm = m0 + wr * 64 + rb2 * 32 + (reg & 3) + 8 * (reg >> 2) + 4 * hi;
                out[(long)mm * KD + nn] = acc[rb2][cb2][reg] + bv;
            }
        }
}

extern "C" void kernel_launch(void* const* d_in, const int* in_sizes, int n_in,
                              void* d_out, int out_size, void* d_ws, size_t ws_size,
                              hipStream_t stream) {
    const float* x  = (const float*)d_in[0];
    const float* Wq = (const float*)d_in[1];
    const float* Wk = (const float*)d_in[2];
    const float* Wv = (const float*)d_in[3];
    const float* Wu = (const float*)d_in[4];
    const float* bu = (const float*)d_in[5];
    float* out = (float*)d_out;

    u16* ws = (u16*)d_ws;
    const size_t SZ = (size_t)NB * NH * TB * HD;   // per-tensor bf16 elems
    u16* Q   = ws;
    u16* Kq  = ws + SZ;
    u16* VT  = ws + 2 * SZ;   // [bh][96][2048]
    u16* O   = ws + 3 * SZ;
    u16* Wub = ws;            // aliases Q (dead after attn; stream-ordered)

    const float inv4 = 1.0f / powf((float)KD, 0.25f);

    qkv_proj<<<dim3(TB / 64, NB * NH), dim3(256), 0, stream>>>(x, Wq, Wk, Wv, Q, Kq, VT, inv4);
    attn<<<dim3(TB / 128 * NB * NH), dim3(256), 0, stream>>>(Q, Kq, VT, O);
    wu_conv<<<dim3((KD * KD) / 1024), dim3(256), 0, stream>>>(Wu, Wub);
    out_gemm<<<dim3((NB * TB / 128) * (KD / 128)), dim3(256), 0, stream>>>(O, Wub, bu, out);
}